// Round 10
// baseline (227.235 us; speedup 1.0000x reference)
//
#include <hip/hip_runtime.h>

#define T_SEQ 4096
#define DMODEL 2048
#define HD 128

typedef float f32x4 __attribute__((ext_vector_type(4)));
typedef _Float16 f16x8 __attribute__((ext_vector_type(8)));

__device__ __forceinline__ unsigned short f2h(float f) {
  union { _Float16 h; unsigned short u; } v;
  v.h = (_Float16)f;
  return v.u;
}

__device__ __forceinline__ unsigned pk2h(float lo, float hi) {
  return (unsigned)f2h(lo) | ((unsigned)f2h(hi) << 16);
}

template <int CTRL>
__device__ __forceinline__ float dppmax(float x) {
  union { float f; int i; } a, b;
  a.f = x;
  b.i = __builtin_amdgcn_update_dpp(a.i, a.i, CTRL, 0xF, 0xF, false);
  return fmaxf(x, b.f);
}
template <int CTRL>
__device__ __forceinline__ float dppadd(float x) {
  union { float f; int i; } a, b;
  a.f = x;
  b.i = __builtin_amdgcn_update_dpp(a.i, a.i, CTRL, 0xF, 0xF, false);
  return x + b.f;
}
__device__ __forceinline__ float red16_max(float x) {
  x = dppmax<0xB1>(x); x = dppmax<0x4E>(x);
  x = dppmax<0x124>(x); x = dppmax<0x128>(x);
  return x;
}
__device__ __forceinline__ float red16_add(float x) {
  x = dppadd<0xB1>(x); x = dppadd<0x4E>(x);
  x = dppadd<0x124>(x); x = dppadd<0x128>(x);
  return x;
}

// ---------------- weight conversion: fp32 -> fp16, concat q/k/v ----------------
__global__ __launch_bounds__(256) void cvt_w_kernel(
    const float* __restrict__ qw, const float* __restrict__ qb,
    const float* __restrict__ kw, const float* __restrict__ kb,
    const float* __restrict__ vw, const float* __restrict__ vb,
    unsigned short* __restrict__ wb, float* __restrict__ biasc) {
  int idx = blockIdx.x * 256 + threadIdx.x;
  int e = idx * 4;
  int row = e >> 11;
  int col = e & 2047;
  const float* src = (row < 128) ? (qw + row * 2048)
                   : (row < 256) ? (kw + (row - 128) * 2048)
                                 : (vw + (row - 256) * 2048);
  float4 v = *(const float4*)(src + col);
  ushort4 o;
  o.x = f2h(v.x); o.y = f2h(v.y); o.z = f2h(v.z); o.w = f2h(v.w);
  *(ushort4*)(wb + e) = o;
  if (blockIdx.x == 0 && threadIdx.x < 384) {
    int n = threadIdx.x;
    biasc[n] = (n < 128) ? qb[n] : (n < 256) ? kb[n - 128] : vb[n - 256];
  }
}

// ---------------- QKV projection: BM=64 x BN=128, grid (256,3) = 3 blocks/CU ----------------
#define SAB 40
__global__ __launch_bounds__(256, 3) void proj_kernel(
    const float* __restrict__ x, const unsigned short* __restrict__ wb,
    const float* __restrict__ biasc, unsigned short* __restrict__ qkv) {
  __shared__ unsigned short sA[64 * SAB];
  __shared__ unsigned short sB[128 * SAB];
  const int tid = threadIdx.x;
  const int lane = tid & 63;
  const int w = tid >> 6;
  const int fr = lane & 15;
  const int g = lane >> 4;
  const int m0 = blockIdx.x * 64;
  const int n0 = blockIdx.y * 128;
  const int wm = (w & 1) * 32;
  const int wn = (w >> 1) * 64;

  const int arow = tid >> 2;           // 0..63
  const int acolA = (tid & 3) * 8;     // 0,8,16,24
  const int brow = tid >> 1;           // 0..127
  const int bcolB = (tid & 1) * 16;    // 0,16
  const float* xp = x + (size_t)(m0 + arow) * DMODEL + acolA;
  const unsigned short* bp = wb + (size_t)(n0 + brow) * DMODEL + bcolB;

  f32x4 acc[2][4] = {};
  float4 ax0 = *(const float4*)(xp);
  float4 ax1 = *(const float4*)(xp + 4);
  uint4 bx0 = *(const uint4*)(bp);
  uint4 bx1 = *(const uint4*)(bp + 8);

  for (int k0 = 0; k0 < DMODEL; k0 += 32) {
    __syncthreads();  // previous iter's frag reads complete
    uint4 pa;
    pa.x = pk2h(ax0.x, ax0.y); pa.y = pk2h(ax0.z, ax0.w);
    pa.z = pk2h(ax1.x, ax1.y); pa.w = pk2h(ax1.z, ax1.w);
    *(uint4*)&sA[arow * SAB + acolA] = pa;
    *(uint4*)&sB[brow * SAB + bcolB] = bx0;
    *(uint4*)&sB[brow * SAB + bcolB + 8] = bx1;
    __syncthreads();

    if (k0 + 32 < DMODEL) {  // loads in flight across the MFMA phase
      ax0 = *(const float4*)(xp + k0 + 32);
      ax1 = *(const float4*)(xp + k0 + 36);
      bx0 = *(const uint4*)(bp + k0 + 32);
      bx1 = *(const uint4*)(bp + k0 + 40);
    }

    f16x8 af[2], bf[4];
#pragma unroll
    for (int i = 0; i < 2; ++i)
      af[i] = *(const f16x8*)&sA[(wm + 16 * i + fr) * SAB + g * 8];
#pragma unroll
    for (int jn = 0; jn < 4; ++jn)
      bf[jn] = *(const f16x8*)&sB[(wn + 16 * jn + fr) * SAB + g * 8];
#pragma unroll
    for (int i = 0; i < 2; ++i)
#pragma unroll
      for (int jn = 0; jn < 4; ++jn)
        acc[i][jn] = __builtin_amdgcn_mfma_f32_16x16x32_f16(af[i], bf[jn], acc[i][jn], 0, 0, 0);
  }

#pragma unroll
  for (int jn = 0; jn < 4; ++jn) {
    int n = n0 + wn + 16 * jn + fr;
    float bias = biasc[n];
#pragma unroll
    for (int i = 0; i < 2; ++i) {
      int mb = m0 + wm + 16 * i + g * 4;
#pragma unroll
      for (int r = 0; r < 4; ++r)
        qkv[(size_t)(mb + r) * 384 + n] = f2h(acc[i][jn][r] + bias);
    }
  }
}

// ---------------- causal flash attention (split-KV, QBLK=64/KVBLK=64) ----------------
// Phase-overlapped: A = {stage V(t) || QK(t) || softmax || P}, B = {stage K(t+1) || PV(t)}.
// V/P contraction permutation sigma(p)=16*(p&3)+(p>>2); V logical block b of row d
// stored at physical block b ^ ((d>>3)&14)  (4-elem blocks) — layouts = round-6 kernel.
#define SKS 136
#define SVS 72
#define SPS 72
__global__ __launch_bounds__(256, 3) void attn_kernel(
    const unsigned short* __restrict__ qkv, float* __restrict__ out,
    float* __restrict__ po, float* __restrict__ pml, int split) {
  __shared__ unsigned short sK[64 * SKS];
  __shared__ unsigned short sVt[128 * SVS];
  __shared__ unsigned short sP[64 * SPS];
  const int id = blockIdx.x;
  const int batch = blockIdx.y;
  int qt, c, nc;
  if (split) {
    if (id < 16)      { qt = id;                c = 0;          nc = 1; }
    else if (id < 48) { qt = 16 + ((id - 16) >> 1); c = (id - 16) & 1; nc = 2; }
    else if (id < 96) { qt = 32 + (id - 48) / 3;    c = (id - 48) % 3; nc = 3; }
    else              { qt = 48 + ((id - 96) >> 2); c = (id - 96) & 3; nc = 4; }
  } else { qt = id; c = 0; nc = 1; }
  const int qbase = qt * 64;
  const int ntl = qt + 1;
  const int t0 = (c * ntl) / nc;
  const int tend = ((c + 1) * ntl) / nc;
  const int tid = threadIdx.x;
  const int lane = tid & 63;
  const int w = tid >> 6;      // wave 0..3, owns q rows [16w, 16w+16)
  const int fr = lane & 15;
  const int g = lane >> 4;
  const int va = tid >> 4;     // 0..15: p-block (4 positions)
  const int vu = tid & 15;     // d-chunk (8 elems)
  const int vblk = ((va ^ (vu & 14)) << 2);
  const unsigned short* qkvb = qkv + (size_t)batch * T_SEQ * 384;

  f16x8 qf[4];
  {
    const unsigned short* qp = qkvb + (size_t)(qbase + 16 * w + fr) * 384 + g * 8;
#pragma unroll
    for (int s = 0; s < 4; ++s) qf[s] = *(const f16x8*)(qp + 32 * s);
  }
  f32x4 o[8] = {};
  float m_r[4], l_r[4];
#pragma unroll
  for (int r = 0; r < 4; ++r) { m_r[r] = -1e30f; l_r[r] = 0.f; }
  const float scale = 0.08838834764831845f;

  uint4 pk[4], pvv[4];
  // prologue: load K(t0), V(t0); stage K(t0); preload K(t0+1)
#pragma unroll
  for (int it = 0; it < 4; ++it) {
    int idx = it * 256 + tid;
    pk[it] = *(const uint4*)(qkvb + (size_t)(t0 * 64 + (idx >> 4)) * 384 + 128 + (idx & 15) * 8);
  }
#pragma unroll
  for (int i = 0; i < 4; ++i)  // V row for position 4*va+i is va+16*i
    pvv[i] = *(const uint4*)(qkvb + (size_t)(t0 * 64 + va + 16 * i) * 384 + 256 + vu * 8);
#pragma unroll
  for (int it = 0; it < 4; ++it) {
    int idx = it * 256 + tid;
    *(uint4*)&sK[(idx >> 4) * SKS + (idx & 15) * 8] = pk[it];
  }
  if (t0 + 1 < tend) {
#pragma unroll
    for (int it = 0; it < 4; ++it) {
      int idx = it * 256 + tid;
      pk[it] = *(const uint4*)(qkvb + (size_t)((t0 + 1) * 64 + (idx >> 4)) * 384 + 128 + (idx & 15) * 8);
    }
  }
  __syncthreads();

  for (int t = t0; t < tend; ++t) {
    const int kbase = t * 64;

    // ---- Phase A: stage V(t) || QK(t) || softmax || P-store ----
    {
      const unsigned* w0 = (const unsigned*)&pvv[0];
      const unsigned* w1 = (const unsigned*)&pvv[1];
      const unsigned* w2 = (const unsigned*)&pvv[2];
      const unsigned* w3 = (const unsigned*)&pvv[3];
#pragma unroll
      for (int j2 = 0; j2 < 4; ++j2) {
        uint2 se, so;
        se.x = __builtin_amdgcn_perm(w1[j2], w0[j2], 0x05040100);
        se.y = __builtin_amdgcn_perm(w3[j2], w2[j2], 0x05040100);
        so.x = __builtin_amdgcn_perm(w1[j2], w0[j2], 0x07060302);
        so.y = __builtin_amdgcn_perm(w3[j2], w2[j2], 0x07060302);
        *(uint2*)&sVt[(8 * vu + 2 * j2) * SVS + vblk] = se;
        *(uint2*)&sVt[(8 * vu + 2 * j2 + 1) * SVS + vblk] = so;
      }
    }
    if (t + 1 < tend) {  // V loads for next tile fly under this tile's compute
#pragma unroll
      for (int i = 0; i < 4; ++i)
        pvv[i] = *(const uint4*)(qkvb + (size_t)((t + 1) * 64 + va + 16 * i) * 384 + 256 + vu * 8);
    }

    f32x4 sacc[4] = {};
    __builtin_amdgcn_s_setprio(1);
#pragma unroll
    for (int ks = 0; ks < 4; ++ks)
#pragma unroll
      for (int tn = 0; tn < 4; ++tn) {
        f16x8 kf = *(const f16x8*)&sK[(16 * tn + fr) * SKS + 32 * ks + g * 8];
        sacc[tn] = __builtin_amdgcn_mfma_f32_16x16x32_f16(qf[ks], kf, sacc[tn], 0, 0, 0);
      }
    __builtin_amdgcn_s_setprio(0);

    const bool diag = (t == qt);
    float pv[4][4];
#pragma unroll
    for (int r = 0; r < 4; ++r) {
      int grow = qbase + 16 * w + g * 4 + r;
      float mx = -1e30f;
#pragma unroll
      for (int tn = 0; tn < 4; ++tn) {
        float s = sacc[tn][r] * scale;
        if (diag && (kbase + 16 * tn + fr) > grow) s = -1e30f;
        pv[tn][r] = s;
        mx = fmaxf(mx, s);
      }
      mx = red16_max(mx);
      if (mx > m_r[r]) {  // rescale only when running max grows
        float alpha = __expf(m_r[r] - mx);
        m_r[r] = mx;
        l_r[r] *= alpha;
#pragma unroll
        for (int nt = 0; nt < 8; ++nt) o[nt][r] *= alpha;
      }
      float rs = 0.f;
#pragma unroll
      for (int tn = 0; tn < 4; ++tn) {
        float p = __expf(pv[tn][r] - m_r[r]);
        pv[tn][r] = p;
        rs += p;
      }
      rs = red16_add(rs);
      l_r[r] += rs;
    }

    // P -> LDS at permuted position p = 4*fr + tn (one b64 per r)
#pragma unroll
    for (int r = 0; r < 4; ++r) {
      uint2 pw;
      pw.x = pk2h(pv[0][r], pv[1][r]);
      pw.y = pk2h(pv[2][r], pv[3][r]);
      *(uint2*)&sP[(16 * w + 4 * g + r) * SPS + 4 * fr] = pw;
    }
    __syncthreads();  // sVt(t)+sP ready; all QK reads of sK(t) done

    // ---- Phase B: stage K(t+1) || PV(t) ----
    if (t + 1 < tend) {
#pragma unroll
      for (int it = 0; it < 4; ++it) {
        int idx = it * 256 + tid;
        *(uint4*)&sK[(idx >> 4) * SKS + (idx & 15) * 8] = pk[it];
      }
      if (t + 2 < tend) {
#pragma unroll
        for (int it = 0; it < 4; ++it) {
          int idx = it * 256 + tid;
          pk[it] = *(const uint4*)(qkvb + (size_t)((t + 2) * 64 + (idx >> 4)) * 384 + 128 + (idx & 15) * 8);
        }
      }
    }
    __builtin_amdgcn_s_setprio(1);
#pragma unroll
    for (int ks = 0; ks < 2; ++ks) {
      f16x8 pa = *(const f16x8*)&sP[(16 * w + fr) * SPS + 32 * ks + 8 * g];
#pragma unroll
      for (int nt = 0; nt < 8; ++nt) {
        int d = 16 * nt + fr;
        int blk = ((8 * ks + 2 * g) ^ ((d >> 3) & 14)) << 2;  // round-6 validated layout
        f16x8 vf = *(const f16x8*)&sVt[d * SVS + blk];
        o[nt] = __builtin_amdgcn_mfma_f32_16x16x32_f16(pa, vf, o[nt], 0, 0, 0);
      }
    }
    __builtin_amdgcn_s_setprio(0);
    __syncthreads();  // PV reads of sVt(t) done; sK(t+1) visible
  }

  if (nc == 1) {
#pragma unroll
    for (int r = 0; r < 4; ++r) {
      float inv = 1.0f / l_r[r];
      int grow = qbase + 16 * w + g * 4 + r;
      float* op = out + ((size_t)batch * T_SEQ + grow) * HD;
#pragma unroll
      for (int nt = 0; nt < 8; ++nt)
        op[16 * nt + fr] = o[nt][r] * inv;
    }
  } else {
    size_t slot = ((size_t)batch * 160 + id) * 64;
#pragma unroll
    for (int r = 0; r < 4; ++r) {
      int lrow = 16 * w + g * 4 + r;
      float* op = po + (slot + lrow) * 128;
#pragma unroll
      for (int nt = 0; nt < 8; ++nt)
        op[16 * nt + fr] = o[nt][r];
      if (fr == 0) {
        pml[(slot + lrow) * 2] = m_r[r];
        pml[(slot + lrow) * 2 + 1] = l_r[r];
      }
    }
  }
}

// ---------------- combine partial chunks (rows with qt >= 16) ----------------
__global__ __launch_bounds__(256) void combine_kernel(
    const float* __restrict__ po, const float* __restrict__ pml,
    float* __restrict__ out) {
  int gr = blockIdx.x * 2 + (threadIdx.x >> 7);
  int d = threadIdx.x & 127;
  int batch = gr / 3072;
  int ridx = gr - batch * 3072;
  int qt = 16 + (ridx >> 6);
  int rr = ridx & 63;
  int nc = 1 + (qt >> 4);
  int sb = (qt < 32) ? 16 + (qt - 16) * 2
         : (qt < 48) ? 48 + (qt - 32) * 3
                     : 96 + (qt - 48) * 4;
  size_t base = ((size_t)batch * 160 + sb) * 64 + rr;
  float mi[4], li[4];
  float M = -1e30f;
#pragma unroll
  for (int i = 0; i < 4; ++i) {
    if (i < nc) {
      mi[i] = pml[(base + (size_t)i * 64) * 2];
      li[i] = pml[(base + (size_t)i * 64) * 2 + 1];
      M = fmaxf(M, mi[i]);
    }
  }
  float L = 0.f, acc = 0.f;
#pragma unroll
  for (int i = 0; i < 4; ++i) {
    if (i < nc) {
      float sc = __expf(mi[i] - M);
      L += li[i] * sc;
      acc += po[(base + (size_t)i * 64) * 128 + d] * sc;
    }
  }
  out[((size_t)batch * T_SEQ + qt * 64 + rr) * HD + d] = acc / L;
}

extern "C" void kernel_launch(void* const* d_in, const int* in_sizes, int n_in,
                              void* d_out, int out_size, void* d_ws, size_t ws_size,
                              hipStream_t stream) {
  const float* x  = (const float*)d_in[0];
  const float* qw = (const float*)d_in[1];
  const float* qb = (const float*)d_in[2];
  const float* kw = (const float*)d_in[3];
  const float* kb = (const float*)d_in[4];
  const float* vw = (const float*)d_in[5];
  const float* vb = (const float*)d_in[6];
  float* out = (float*)d_out;

  unsigned short* qkv = (unsigned short*)d_ws;              // 12,582,912 B
  unsigned short* wb  = qkv + (size_t)16384 * 384;          //  1,572,864 B
  float* biasc = (float*)(wb + (size_t)384 * 2048);         //      1,536 B
  float* po  = (float*)((char*)d_ws + 14157312);            // 640*64*128*4 = 20,971,520 B
  float* pml = po + (size_t)640 * 64 * 128;                 // 640*64*2*4 = 327,680 B
  size_t need = 14157312 + (size_t)640 * 64 * 128 * 4 + (size_t)640 * 64 * 2 * 4;
  int split = (ws_size >= need) ? 1 : 0;

  cvt_w_kernel<<<768, 256, 0, stream>>>(qw, qb, kw, kb, vw, vb, wb, biasc);
  proj_kernel<<<dim3(256, 3), 256, 0, stream>>>(x, wb, biasc, qkv);
  attn_kernel<<<dim3(split ? 160 : 64, 4), 256, 0, stream>>>(qkv, out, po, pml, split);
  if (split)
    combine_kernel<<<6144, 256, 0, stream>>>(po, pml, out);
}

// Round 11
// 166.251 us; speedup vs baseline: 1.3668x; 1.3668x over previous
//
#include <hip/hip_runtime.h>

#define T_SEQ 4096
#define DMODEL 2048
#define HD 128

typedef float f32x4 __attribute__((ext_vector_type(4)));
typedef _Float16 f16x8 __attribute__((ext_vector_type(8)));

__device__ __forceinline__ unsigned short f2h(float f) {
  union { _Float16 h; unsigned short u; } v;
  v.h = (_Float16)f;
  return v.u;
}

__device__ __forceinline__ unsigned pk2h(float lo, float hi) {
  return (unsigned)f2h(lo) | ((unsigned)f2h(hi) << 16);
}

template <int CTRL>
__device__ __forceinline__ float dppmax(float x) {
  union { float f; int i; } a, b;
  a.f = x;
  b.i = __builtin_amdgcn_update_dpp(a.i, a.i, CTRL, 0xF, 0xF, false);
  return fmaxf(x, b.f);
}
template <int CTRL>
__device__ __forceinline__ float dppadd(float x) {
  union { float f; int i; } a, b;
  a.f = x;
  b.i = __builtin_amdgcn_update_dpp(a.i, a.i, CTRL, 0xF, 0xF, false);
  return x + b.f;
}
__device__ __forceinline__ float red16_max(float x) {
  x = dppmax<0xB1>(x); x = dppmax<0x4E>(x);
  x = dppmax<0x124>(x); x = dppmax<0x128>(x);
  return x;
}
__device__ __forceinline__ float red16_add(float x) {
  x = dppadd<0xB1>(x); x = dppadd<0x4E>(x);
  x = dppadd<0x124>(x); x = dppadd<0x128>(x);
  return x;
}

// ---------------- weight conversion: fp32 -> fp16, concat q/k/v ----------------
__global__ __launch_bounds__(256) void cvt_w_kernel(
    const float* __restrict__ qw, const float* __restrict__ qb,
    const float* __restrict__ kw, const float* __restrict__ kb,
    const float* __restrict__ vw, const float* __restrict__ vb,
    unsigned short* __restrict__ wb, float* __restrict__ biasc) {
  int idx = blockIdx.x * 256 + threadIdx.x;
  int e = idx * 4;
  int row = e >> 11;
  int col = e & 2047;
  const float* src = (row < 128) ? (qw + row * 2048)
                   : (row < 256) ? (kw + (row - 128) * 2048)
                                 : (vw + (row - 256) * 2048);
  float4 v = *(const float4*)(src + col);
  ushort4 o;
  o.x = f2h(v.x); o.y = f2h(v.y); o.z = f2h(v.z); o.w = f2h(v.w);
  *(ushort4*)(wb + e) = o;
  if (blockIdx.x == 0 && threadIdx.x < 384) {
    int n = threadIdx.x;
    biasc[n] = (n < 128) ? qb[n] : (n < 256) ? kb[n - 128] : vb[n - 256];
  }
}

// ---------------- QKV projection: BM=64 x BN=128, grid (256,3) = 3 blocks/CU ----------------
#define SAB 40
__global__ __launch_bounds__(256, 3) void proj_kernel(
    const float* __restrict__ x, const unsigned short* __restrict__ wb,
    const float* __restrict__ biasc, unsigned short* __restrict__ qkv) {
  __shared__ unsigned short sA[64 * SAB];
  __shared__ unsigned short sB[128 * SAB];
  const int tid = threadIdx.x;
  const int lane = tid & 63;
  const int w = tid >> 6;
  const int fr = lane & 15;
  const int g = lane >> 4;
  const int m0 = blockIdx.x * 64;
  const int n0 = blockIdx.y * 128;
  const int wm = (w & 1) * 32;
  const int wn = (w >> 1) * 64;

  const int arow = tid >> 2;           // 0..63
  const int acolA = (tid & 3) * 8;     // 0,8,16,24
  const int brow = tid >> 1;           // 0..127
  const int bcolB = (tid & 1) * 16;    // 0,16
  const float* xp = x + (size_t)(m0 + arow) * DMODEL + acolA;
  const unsigned short* bp = wb + (size_t)(n0 + brow) * DMODEL + bcolB;

  f32x4 acc[2][4] = {};
  float4 ax0 = *(const float4*)(xp);
  float4 ax1 = *(const float4*)(xp + 4);
  uint4 bx0 = *(const uint4*)(bp);
  uint4 bx1 = *(const uint4*)(bp + 8);

  for (int k0 = 0; k0 < DMODEL; k0 += 32) {
    __syncthreads();  // previous iter's frag reads complete
    uint4 pa;
    pa.x = pk2h(ax0.x, ax0.y); pa.y = pk2h(ax0.z, ax0.w);
    pa.z = pk2h(ax1.x, ax1.y); pa.w = pk2h(ax1.z, ax1.w);
    *(uint4*)&sA[arow * SAB + acolA] = pa;
    *(uint4*)&sB[brow * SAB + bcolB] = bx0;
    *(uint4*)&sB[brow * SAB + bcolB + 8] = bx1;
    __syncthreads();

    if (k0 + 32 < DMODEL) {  // loads in flight across the MFMA phase
      ax0 = *(const float4*)(xp + k0 + 32);
      ax1 = *(const float4*)(xp + k0 + 36);
      bx0 = *(const uint4*)(bp + k0 + 32);
      bx1 = *(const uint4*)(bp + k0 + 40);
    }

    f16x8 af[2], bf[4];
#pragma unroll
    for (int i = 0; i < 2; ++i)
      af[i] = *(const f16x8*)&sA[(wm + 16 * i + fr) * SAB + g * 8];
#pragma unroll
    for (int jn = 0; jn < 4; ++jn)
      bf[jn] = *(const f16x8*)&sB[(wn + 16 * jn + fr) * SAB + g * 8];
#pragma unroll
    for (int i = 0; i < 2; ++i)
#pragma unroll
      for (int jn = 0; jn < 4; ++jn)
        acc[i][jn] = __builtin_amdgcn_mfma_f32_16x16x32_f16(af[i], bf[jn], acc[i][jn], 0, 0, 0);
  }

#pragma unroll
  for (int jn = 0; jn < 4; ++jn) {
    int n = n0 + wn + 16 * jn + fr;
    float bias = biasc[n];
#pragma unroll
    for (int i = 0; i < 2; ++i) {
      int mb = m0 + wm + 16 * i + g * 4;
#pragma unroll
      for (int r = 0; r < 4; ++r)
        qkv[(size_t)(mb + r) * 384 + n] = f2h(acc[i][jn][r] + bias);
    }
  }
}

// ---------------- causal flash attention (split-KV, QBLK=64/KVBLK=64) ----------------
// Phase-overlapped: A = {stage V(t) || QK(t) || softmax || P}, B = {stage K(t+1) || PV(t)}.
// V/P contraction permutation sigma(p)=16*(p&3)+(p>>2); V logical block b of row d
// stored at physical block b ^ ((d>>3)&14)  (4-elem blocks) — layouts = round-6 kernel.
// NOTE: no waves-per-EU hint — (256,3) capped VGPRs at 84 and spilled ~200 MB to scratch.
#define SKS 136
#define SVS 72
#define SPS 72
__global__ __launch_bounds__(256) void attn_kernel(
    const unsigned short* __restrict__ qkv, float* __restrict__ out,
    float* __restrict__ po, float* __restrict__ pml, int split) {
  __shared__ unsigned short sK[64 * SKS];
  __shared__ unsigned short sVt[128 * SVS];
  __shared__ unsigned short sP[64 * SPS];
  const int id = blockIdx.x;
  const int batch = blockIdx.y;
  int qt, c, nc;
  if (split) {
    if (id < 16)      { qt = id;                c = 0;          nc = 1; }
    else if (id < 48) { qt = 16 + ((id - 16) >> 1); c = (id - 16) & 1; nc = 2; }
    else if (id < 96) { qt = 32 + (id - 48) / 3;    c = (id - 48) % 3; nc = 3; }
    else              { qt = 48 + ((id - 96) >> 2); c = (id - 96) & 3; nc = 4; }
  } else { qt = id; c = 0; nc = 1; }
  const int qbase = qt * 64;
  const int ntl = qt + 1;
  const int t0 = (c * ntl) / nc;
  const int tend = ((c + 1) * ntl) / nc;
  const int tid = threadIdx.x;
  const int lane = tid & 63;
  const int w = tid >> 6;      // wave 0..3, owns q rows [16w, 16w+16)
  const int fr = lane & 15;
  const int g = lane >> 4;
  const int va = tid >> 4;     // 0..15: p-block (4 positions)
  const int vu = tid & 15;     // d-chunk (8 elems)
  const int vblk = ((va ^ (vu & 14)) << 2);
  const unsigned short* qkvb = qkv + (size_t)batch * T_SEQ * 384;

  f16x8 qf[4];
  {
    const unsigned short* qp = qkvb + (size_t)(qbase + 16 * w + fr) * 384 + g * 8;
#pragma unroll
    for (int s = 0; s < 4; ++s) qf[s] = *(const f16x8*)(qp + 32 * s);
  }
  f32x4 o[8] = {};
  float m_r[4], l_r[4];
#pragma unroll
  for (int r = 0; r < 4; ++r) { m_r[r] = -1e30f; l_r[r] = 0.f; }
  const float scale = 0.08838834764831845f;

  uint4 pk[4], pvv[4];
  // prologue: load K(t0), V(t0); stage K(t0); preload K(t0+1)
#pragma unroll
  for (int it = 0; it < 4; ++it) {
    int idx = it * 256 + tid;
    pk[it] = *(const uint4*)(qkvb + (size_t)(t0 * 64 + (idx >> 4)) * 384 + 128 + (idx & 15) * 8);
  }
#pragma unroll
  for (int i = 0; i < 4; ++i)  // V row for position 4*va+i is va+16*i
    pvv[i] = *(const uint4*)(qkvb + (size_t)(t0 * 64 + va + 16 * i) * 384 + 256 + vu * 8);
#pragma unroll
  for (int it = 0; it < 4; ++it) {
    int idx = it * 256 + tid;
    *(uint4*)&sK[(idx >> 4) * SKS + (idx & 15) * 8] = pk[it];
  }
  if (t0 + 1 < tend) {
#pragma unroll
    for (int it = 0; it < 4; ++it) {
      int idx = it * 256 + tid;
      pk[it] = *(const uint4*)(qkvb + (size_t)((t0 + 1) * 64 + (idx >> 4)) * 384 + 128 + (idx & 15) * 8);
    }
  }
  __syncthreads();

  for (int t = t0; t < tend; ++t) {
    const int kbase = t * 64;

    // ---- Phase A: stage V(t) || QK(t) || softmax || P-store ----
    {
      const unsigned* w0 = (const unsigned*)&pvv[0];
      const unsigned* w1 = (const unsigned*)&pvv[1];
      const unsigned* w2 = (const unsigned*)&pvv[2];
      const unsigned* w3 = (const unsigned*)&pvv[3];
#pragma unroll
      for (int j2 = 0; j2 < 4; ++j2) {
        uint2 se, so;
        se.x = __builtin_amdgcn_perm(w1[j2], w0[j2], 0x05040100);
        se.y = __builtin_amdgcn_perm(w3[j2], w2[j2], 0x05040100);
        so.x = __builtin_amdgcn_perm(w1[j2], w0[j2], 0x07060302);
        so.y = __builtin_amdgcn_perm(w3[j2], w2[j2], 0x07060302);
        *(uint2*)&sVt[(8 * vu + 2 * j2) * SVS + vblk] = se;
        *(uint2*)&sVt[(8 * vu + 2 * j2 + 1) * SVS + vblk] = so;
      }
    }
    if (t + 1 < tend) {  // V loads for next tile fly under this tile's compute
#pragma unroll
      for (int i = 0; i < 4; ++i)
        pvv[i] = *(const uint4*)(qkvb + (size_t)((t + 1) * 64 + va + 16 * i) * 384 + 256 + vu * 8);
    }

    f32x4 sacc[4] = {};
    __builtin_amdgcn_s_setprio(1);
#pragma unroll
    for (int ks = 0; ks < 4; ++ks)
#pragma unroll
      for (int tn = 0; tn < 4; ++tn) {
        f16x8 kf = *(const f16x8*)&sK[(16 * tn + fr) * SKS + 32 * ks + g * 8];
        sacc[tn] = __builtin_amdgcn_mfma_f32_16x16x32_f16(qf[ks], kf, sacc[tn], 0, 0, 0);
      }
    __builtin_amdgcn_s_setprio(0);

    const bool diag = (t == qt);
    float pv[4][4];
#pragma unroll
    for (int r = 0; r < 4; ++r) {
      int grow = qbase + 16 * w + g * 4 + r;
      float mx = -1e30f;
#pragma unroll
      for (int tn = 0; tn < 4; ++tn) {
        float s = sacc[tn][r] * scale;
        if (diag && (kbase + 16 * tn + fr) > grow) s = -1e30f;
        pv[tn][r] = s;
        mx = fmaxf(mx, s);
      }
      mx = red16_max(mx);
      if (mx > m_r[r]) {  // rescale only when running max grows
        float alpha = __expf(m_r[r] - mx);
        m_r[r] = mx;
        l_r[r] *= alpha;
#pragma unroll
        for (int nt = 0; nt < 8; ++nt) o[nt][r] *= alpha;
      }
      float rs = 0.f;
#pragma unroll
      for (int tn = 0; tn < 4; ++tn) {
        float p = __expf(pv[tn][r] - m_r[r]);
        pv[tn][r] = p;
        rs += p;
      }
      rs = red16_add(rs);
      l_r[r] += rs;
    }

    // P -> LDS at permuted position p = 4*fr + tn (one b64 per r)
#pragma unroll
    for (int r = 0; r < 4; ++r) {
      uint2 pw;
      pw.x = pk2h(pv[0][r], pv[1][r]);
      pw.y = pk2h(pv[2][r], pv[3][r]);
      *(uint2*)&sP[(16 * w + 4 * g + r) * SPS + 4 * fr] = pw;
    }
    __syncthreads();  // sVt(t)+sP ready; all QK reads of sK(t) done

    // ---- Phase B: stage K(t+1) || PV(t) ----
    if (t + 1 < tend) {
#pragma unroll
      for (int it = 0; it < 4; ++it) {
        int idx = it * 256 + tid;
        *(uint4*)&sK[(idx >> 4) * SKS + (idx & 15) * 8] = pk[it];
      }
      if (t + 2 < tend) {
#pragma unroll
        for (int it = 0; it < 4; ++it) {
          int idx = it * 256 + tid;
          pk[it] = *(const uint4*)(qkvb + (size_t)((t + 2) * 64 + (idx >> 4)) * 384 + 128 + (idx & 15) * 8);
        }
      }
    }
    __builtin_amdgcn_s_setprio(1);
#pragma unroll
    for (int ks = 0; ks < 2; ++ks) {
      f16x8 pa = *(const f16x8*)&sP[(16 * w + fr) * SPS + 32 * ks + 8 * g];
#pragma unroll
      for (int nt = 0; nt < 8; ++nt) {
        int d = 16 * nt + fr;
        int blk = ((8 * ks + 2 * g) ^ ((d >> 3) & 14)) << 2;  // round-6 validated layout
        f16x8 vf = *(const f16x8*)&sVt[d * SVS + blk];
        o[nt] = __builtin_amdgcn_mfma_f32_16x16x32_f16(pa, vf, o[nt], 0, 0, 0);
      }
    }
    __builtin_amdgcn_s_setprio(0);
    __syncthreads();  // PV reads of sVt(t) done; sK(t+1) visible
  }

  if (nc == 1) {
#pragma unroll
    for (int r = 0; r < 4; ++r) {
      float inv = 1.0f / l_r[r];
      int grow = qbase + 16 * w + g * 4 + r;
      float* op = out + ((size_t)batch * T_SEQ + grow) * HD;
#pragma unroll
      for (int nt = 0; nt < 8; ++nt)
        op[16 * nt + fr] = o[nt][r] * inv;
    }
  } else {
    size_t slot = ((size_t)batch * 160 + id) * 64;
#pragma unroll
    for (int r = 0; r < 4; ++r) {
      int lrow = 16 * w + g * 4 + r;
      float* op = po + (slot + lrow) * 128;
#pragma unroll
      for (int nt = 0; nt < 8; ++nt)
        op[16 * nt + fr] = o[nt][r];
      if (fr == 0) {
        pml[(slot + lrow) * 2] = m_r[r];
        pml[(slot + lrow) * 2 + 1] = l_r[r];
      }
    }
  }
}

// ---------------- combine partial chunks (rows with qt >= 16) ----------------
__global__ __launch_bounds__(256) void combine_kernel(
    const float* __restrict__ po, const float* __restrict__ pml,
    float* __restrict__ out) {
  int gr = blockIdx.x * 2 + (threadIdx.x >> 7);
  int d = threadIdx.x & 127;
  int batch = gr / 3072;
  int ridx = gr - batch * 3072;
  int qt = 16 + (ridx >> 6);
  int rr = ridx & 63;
  int nc = 1 + (qt >> 4);
  int sb = (qt < 32) ? 16 + (qt - 16) * 2
         : (qt < 48) ? 48 + (qt - 32) * 3
                     : 96 + (qt - 48) * 4;
  size_t base = ((size_t)batch * 160 + sb) * 64 + rr;
  float mi[4], li[4];
  float M = -1e30f;
#pragma unroll
  for (int i = 0; i < 4; ++i) {
    if (i < nc) {
      mi[i] = pml[(base + (size_t)i * 64) * 2];
      li[i] = pml[(base + (size_t)i * 64) * 2 + 1];
      M = fmaxf(M, mi[i]);
    }
  }
  float L = 0.f, acc = 0.f;
#pragma unroll
  for (int i = 0; i < 4; ++i) {
    if (i < nc) {
      float sc = __expf(mi[i] - M);
      L += li[i] * sc;
      acc += po[(base + (size_t)i * 64) * 128 + d] * sc;
    }
  }
  out[((size_t)batch * T_SEQ + qt * 64 + rr) * HD + d] = acc / L;
}

extern "C" void kernel_launch(void* const* d_in, const int* in_sizes, int n_in,
                              void* d_out, int out_size, void* d_ws, size_t ws_size,
                              hipStream_t stream) {
  const float* x  = (const float*)d_in[0];
  const float* qw = (const float*)d_in[1];
  const float* qb = (const float*)d_in[2];
  const float* kw = (const float*)d_in[3];
  const float* kb = (const float*)d_in[4];
  const float* vw = (const float*)d_in[5];
  const float* vb = (const float*)d_in[6];
  float* out = (float*)d_out;

  unsigned short* qkv = (unsigned short*)d_ws;              // 12,582,912 B
  unsigned short* wb  = qkv + (size_t)16384 * 384;          //  1,572,864 B
  float* biasc = (float*)(wb + (size_t)384 * 2048);         //      1,536 B
  float* po  = (float*)((char*)d_ws + 14157312);            // 640*64*128*4 = 20,971,520 B
  float* pml = po + (size_t)640 * 64 * 128;                 // 640*64*2*4 = 327,680 B
  size_t need = 14157312 + (size_t)640 * 64 * 128 * 4 + (size_t)640 * 64 * 2 * 4;
  int split = (ws_size >= need) ? 1 : 0;

  cvt_w_kernel<<<768, 256, 0, stream>>>(qw, qb, kw, kb, vw, vb, wb, biasc);
  proj_kernel<<<dim3(256, 3), 256, 0, stream>>>(x, wb, biasc, qkv);
  attn_kernel<<<dim3(split ? 160 : 64, 4), 256, 0, stream>>>(qkv, out, po, pml, split);
  if (split)
    combine_kernel<<<6144, 256, 0, stream>>>(po, pml, out);
}

// Round 12
// 141.596 us; speedup vs baseline: 1.6048x; 1.1741x over previous
//
#include <hip/hip_runtime.h>

#define T_SEQ 4096
#define DMODEL 2048
#define HD 128

typedef float f32x4 __attribute__((ext_vector_type(4)));
typedef _Float16 f16x8 __attribute__((ext_vector_type(8)));

__device__ __forceinline__ unsigned short f2h(float f) {
  union { _Float16 h; unsigned short u; } v;
  v.h = (_Float16)f;
  return v.u;
}

__device__ __forceinline__ unsigned pk2h(float lo, float hi) {
  return (unsigned)f2h(lo) | ((unsigned)f2h(hi) << 16);
}

template <int CTRL>
__device__ __forceinline__ float dppmax(float x) {
  union { float f; int i; } a, b;
  a.f = x;
  b.i = __builtin_amdgcn_update_dpp(a.i, a.i, CTRL, 0xF, 0xF, false);
  return fmaxf(x, b.f);
}
template <int CTRL>
__device__ __forceinline__ float dppadd(float x) {
  union { float f; int i; } a, b;
  a.f = x;
  b.i = __builtin_amdgcn_update_dpp(a.i, a.i, CTRL, 0xF, 0xF, false);
  return x + b.f;
}
__device__ __forceinline__ float red16_max(float x) {
  x = dppmax<0xB1>(x); x = dppmax<0x4E>(x);
  x = dppmax<0x124>(x); x = dppmax<0x128>(x);
  return x;
}
__device__ __forceinline__ float red16_add(float x) {
  x = dppadd<0xB1>(x); x = dppadd<0x4E>(x);
  x = dppadd<0x124>(x); x = dppadd<0x128>(x);
  return x;
}

// ---------------- weight conversion: fp32 -> fp16, concat q/k/v ----------------
__global__ __launch_bounds__(256) void cvt_w_kernel(
    const float* __restrict__ qw, const float* __restrict__ qb,
    const float* __restrict__ kw, const float* __restrict__ kb,
    const float* __restrict__ vw, const float* __restrict__ vb,
    unsigned short* __restrict__ wb, float* __restrict__ biasc) {
  int idx = blockIdx.x * 256 + threadIdx.x;
  int e = idx * 4;
  int row = e >> 11;
  int col = e & 2047;
  const float* src = (row < 128) ? (qw + row * 2048)
                   : (row < 256) ? (kw + (row - 128) * 2048)
                                 : (vw + (row - 256) * 2048);
  float4 v = *(const float4*)(src + col);
  ushort4 o;
  o.x = f2h(v.x); o.y = f2h(v.y); o.z = f2h(v.z); o.w = f2h(v.w);
  *(ushort4*)(wb + e) = o;
  if (blockIdx.x == 0 && threadIdx.x < 384) {
    int n = threadIdx.x;
    biasc[n] = (n < 128) ? qb[n] : (n < 256) ? kb[n - 128] : vb[n - 256];
  }
}

// ---------------- QKV projection: BM=64 x BN=128, grid (256,3) = 3 blocks/CU ----------------
#define SAB 40
__global__ __launch_bounds__(256, 3) void proj_kernel(
    const float* __restrict__ x, const unsigned short* __restrict__ wb,
    const float* __restrict__ biasc, unsigned short* __restrict__ qkv) {
  __shared__ unsigned short sA[64 * SAB];
  __shared__ unsigned short sB[128 * SAB];
  const int tid = threadIdx.x;
  const int lane = tid & 63;
  const int w = tid >> 6;
  const int fr = lane & 15;
  const int g = lane >> 4;
  const int m0 = blockIdx.x * 64;
  const int n0 = blockIdx.y * 128;
  const int wm = (w & 1) * 32;
  const int wn = (w >> 1) * 64;

  const int arow = tid >> 2;           // 0..63
  const int acolA = (tid & 3) * 8;     // 0,8,16,24
  const int brow = tid >> 1;           // 0..127
  const int bcolB = (tid & 1) * 16;    // 0,16
  const float* xp = x + (size_t)(m0 + arow) * DMODEL + acolA;
  const unsigned short* bp = wb + (size_t)(n0 + brow) * DMODEL + bcolB;

  f32x4 acc[2][4] = {};
  float4 ax0 = *(const float4*)(xp);
  float4 ax1 = *(const float4*)(xp + 4);
  uint4 bx0 = *(const uint4*)(bp);
  uint4 bx1 = *(const uint4*)(bp + 8);

  for (int k0 = 0; k0 < DMODEL; k0 += 32) {
    __syncthreads();  // previous iter's frag reads complete
    uint4 pa;
    pa.x = pk2h(ax0.x, ax0.y); pa.y = pk2h(ax0.z, ax0.w);
    pa.z = pk2h(ax1.x, ax1.y); pa.w = pk2h(ax1.z, ax1.w);
    *(uint4*)&sA[arow * SAB + acolA] = pa;
    *(uint4*)&sB[brow * SAB + bcolB] = bx0;
    *(uint4*)&sB[brow * SAB + bcolB + 8] = bx1;
    __syncthreads();

    if (k0 + 32 < DMODEL) {  // loads in flight across the MFMA phase
      ax0 = *(const float4*)(xp + k0 + 32);
      ax1 = *(const float4*)(xp + k0 + 36);
      bx0 = *(const uint4*)(bp + k0 + 32);
      bx1 = *(const uint4*)(bp + k0 + 40);
    }

    f16x8 af[2], bf[4];
#pragma unroll
    for (int i = 0; i < 2; ++i)
      af[i] = *(const f16x8*)&sA[(wm + 16 * i + fr) * SAB + g * 8];
#pragma unroll
    for (int jn = 0; jn < 4; ++jn)
      bf[jn] = *(const f16x8*)&sB[(wn + 16 * jn + fr) * SAB + g * 8];
#pragma unroll
    for (int i = 0; i < 2; ++i)
#pragma unroll
      for (int jn = 0; jn < 4; ++jn)
        acc[i][jn] = __builtin_amdgcn_mfma_f32_16x16x32_f16(af[i], bf[jn], acc[i][jn], 0, 0, 0);
  }

#pragma unroll
  for (int jn = 0; jn < 4; ++jn) {
    int n = n0 + wn + 16 * jn + fr;
    float bias = biasc[n];
#pragma unroll
    for (int i = 0; i < 2; ++i) {
      int mb = m0 + wm + 16 * i + g * 4;
#pragma unroll
      for (int r = 0; r < 4; ++r)
        qkv[(size_t)(mb + r) * 384 + n] = f2h(acc[i][jn][r] + bias);
    }
  }
}

// ---------------- causal flash attention (split-KV, QBLK=64/KVBLK=64) ----------------
// Round-6 validated structure. waves_per_eu(2,3): LDS caps residency at 3 blocks/CU
// anyway, so cap the allocator's occupancy target at 3/EU -> ~170 VGPR budget, no spill
// (default heuristic spilled ~30-200 MB chasing 4-6 waves/EU it could never get).
#define SKS 136
#define SVS 72
#define SPS 72
__global__ __launch_bounds__(256) __attribute__((amdgpu_waves_per_eu(2, 3)))
void attn_kernel(
    const unsigned short* __restrict__ qkv, float* __restrict__ out,
    float* __restrict__ po, float* __restrict__ pml, int split) {
  __shared__ unsigned short sK[64 * SKS];
  __shared__ unsigned short sVt[128 * SVS];  // [d][p-blocks, XOR-swizzled]
  __shared__ unsigned short sP[64 * SPS];    // [q_local][p]
  const int id = blockIdx.x;
  const int batch = blockIdx.y;
  int qt, c, nc;
  if (split) {
    if (id < 16)      { qt = id;                c = 0;          nc = 1; }
    else if (id < 48) { qt = 16 + ((id - 16) >> 1); c = (id - 16) & 1; nc = 2; }
    else if (id < 96) { qt = 32 + (id - 48) / 3;    c = (id - 48) % 3; nc = 3; }
    else              { qt = 48 + ((id - 96) >> 2); c = (id - 96) & 3; nc = 4; }
  } else { qt = id; c = 0; nc = 1; }
  const int qbase = qt * 64;
  const int ntl = qt + 1;
  const int t0 = (c * ntl) / nc;
  const int tend = ((c + 1) * ntl) / nc;
  const int tid = threadIdx.x;
  const int lane = tid & 63;
  const int w = tid >> 6;      // wave 0..3, owns q rows [16w, 16w+16)
  const int fr = lane & 15;
  const int g = lane >> 4;
  const int va = tid >> 4;     // 0..15: p-block (4 positions)
  const int vu = tid & 15;     // d-chunk (8 elems)
  const int vblk = ((va ^ (vu & 14)) << 2);
  const unsigned short* qkvb = qkv + (size_t)batch * T_SEQ * 384;

  f16x8 qf[4];
  {
    const unsigned short* qp = qkvb + (size_t)(qbase + 16 * w + fr) * 384 + g * 8;
#pragma unroll
    for (int s = 0; s < 4; ++s) qf[s] = *(const f16x8*)(qp + 32 * s);
  }
  f32x4 o[8] = {};
  float m_r[4], l_r[4];
#pragma unroll
  for (int r = 0; r < 4; ++r) { m_r[r] = -1e30f; l_r[r] = 0.f; }
  const float scale = 0.08838834764831845f;

  // prefetch first tile into registers
  uint4 pk[4], pvv[4];
#pragma unroll
  for (int it = 0; it < 4; ++it) {
    int idx = it * 256 + tid;
    pk[it] = *(const uint4*)(qkvb + (size_t)(t0 * 64 + (idx >> 4)) * 384 + 128 + (idx & 15) * 8);
  }
#pragma unroll
  for (int i = 0; i < 4; ++i)  // V row for position 4*va+i is va+16*i
    pvv[i] = *(const uint4*)(qkvb + (size_t)(t0 * 64 + va + 16 * i) * 384 + 256 + vu * 8);

  for (int t = t0; t < tend; ++t) {
    const int kbase = t * 64;
    __syncthreads();  // previous iter's LDS reads complete
#pragma unroll
    for (int it = 0; it < 4; ++it) {
      int idx = it * 256 + tid;
      *(uint4*)&sK[(idx >> 4) * SKS + (idx & 15) * 8] = pk[it];
    }
    {
      const unsigned* w0 = (const unsigned*)&pvv[0];
      const unsigned* w1 = (const unsigned*)&pvv[1];
      const unsigned* w2 = (const unsigned*)&pvv[2];
      const unsigned* w3 = (const unsigned*)&pvv[3];
#pragma unroll
      for (int j2 = 0; j2 < 4; ++j2) {
        uint2 se, so;
        se.x = __builtin_amdgcn_perm(w1[j2], w0[j2], 0x05040100);
        se.y = __builtin_amdgcn_perm(w3[j2], w2[j2], 0x05040100);
        so.x = __builtin_amdgcn_perm(w1[j2], w0[j2], 0x07060302);
        so.y = __builtin_amdgcn_perm(w3[j2], w2[j2], 0x07060302);
        *(uint2*)&sVt[(8 * vu + 2 * j2) * SVS + vblk] = se;
        *(uint2*)&sVt[(8 * vu + 2 * j2 + 1) * SVS + vblk] = so;
      }
    }
    __syncthreads();

    if (t + 1 < tend) {  // overlap next tile's loads with compute below
#pragma unroll
      for (int it = 0; it < 4; ++it) {
        int idx = it * 256 + tid;
        pk[it] = *(const uint4*)(qkvb + (size_t)((t + 1) * 64 + (idx >> 4)) * 384 + 128 + (idx & 15) * 8);
      }
#pragma unroll
      for (int i = 0; i < 4; ++i)
        pvv[i] = *(const uint4*)(qkvb + (size_t)((t + 1) * 64 + va + 16 * i) * 384 + 256 + vu * 8);
    }

    // S = Q K^T
    f32x4 sacc[4] = {};
#pragma unroll
    for (int ks = 0; ks < 4; ++ks)
#pragma unroll
      for (int tn = 0; tn < 4; ++tn) {
        f16x8 kf = *(const f16x8*)&sK[(16 * tn + fr) * SKS + 32 * ks + g * 8];
        sacc[tn] = __builtin_amdgcn_mfma_f32_16x16x32_f16(qf[ks], kf, sacc[tn], 0, 0, 0);
      }

    const bool diag = (t == qt);
    float pv[4][4];
#pragma unroll
    for (int r = 0; r < 4; ++r) {
      int grow = qbase + 16 * w + g * 4 + r;
      float mx = -1e30f;
#pragma unroll
      for (int tn = 0; tn < 4; ++tn) {
        float s = sacc[tn][r] * scale;
        if (diag && (kbase + 16 * tn + fr) > grow) s = -1e30f;
        pv[tn][r] = s;
        mx = fmaxf(mx, s);
      }
      mx = red16_max(mx);
      float mnew = fmaxf(m_r[r], mx);
      float alpha = __expf(m_r[r] - mnew);
      m_r[r] = mnew;
      float rs = 0.f;
#pragma unroll
      for (int tn = 0; tn < 4; ++tn) {
        float p = __expf(pv[tn][r] - mnew);
        pv[tn][r] = p;
        rs += p;
      }
      rs = red16_add(rs);
      l_r[r] = l_r[r] * alpha + rs;
#pragma unroll
      for (int nt = 0; nt < 8; ++nt) o[nt][r] *= alpha;
    }

    // P -> LDS at permuted position p = 4*fr + tn (one b64 per r)
#pragma unroll
    for (int r = 0; r < 4; ++r) {
      uint2 pw;
      pw.x = pk2h(pv[0][r], pv[1][r]);
      pw.y = pk2h(pv[2][r], pv[3][r]);
      *(uint2*)&sP[(16 * w + 4 * g + r) * SPS + 4 * fr] = pw;
    }

    // O += P V (contraction over permuted positions)
#pragma unroll
    for (int ks = 0; ks < 2; ++ks) {
      f16x8 pa = *(const f16x8*)&sP[(16 * w + fr) * SPS + 32 * ks + 8 * g];
#pragma unroll
      for (int nt = 0; nt < 8; ++nt) {
        int d = 16 * nt + fr;
        int blk = ((8 * ks + 2 * g) ^ ((d >> 3) & 14)) << 2;
        f16x8 vf = *(const f16x8*)&sVt[d * SVS + blk];
        o[nt] = __builtin_amdgcn_mfma_f32_16x16x32_f16(pa, vf, o[nt], 0, 0, 0);
      }
    }
  }

  if (nc == 1) {
#pragma unroll
    for (int r = 0; r < 4; ++r) {
      float inv = 1.0f / l_r[r];
      int grow = qbase + 16 * w + g * 4 + r;
      float* op = out + ((size_t)batch * T_SEQ + grow) * HD;
#pragma unroll
      for (int nt = 0; nt < 8; ++nt)
        op[16 * nt + fr] = o[nt][r] * inv;
    }
  } else {
    size_t slot = ((size_t)batch * 160 + id) * 64;
#pragma unroll
    for (int r = 0; r < 4; ++r) {
      int lrow = 16 * w + g * 4 + r;
      float* op = po + (slot + lrow) * 128;
#pragma unroll
      for (int nt = 0; nt < 8; ++nt)
        op[16 * nt + fr] = o[nt][r];
      if (fr == 0) {
        pml[(slot + lrow) * 2] = m_r[r];
        pml[(slot + lrow) * 2 + 1] = l_r[r];
      }
    }
  }
}

// ---------------- combine partial chunks (rows with qt >= 16) ----------------
__global__ __launch_bounds__(256) void combine_kernel(
    const float* __restrict__ po, const float* __restrict__ pml,
    float* __restrict__ out) {
  int gr = blockIdx.x * 2 + (threadIdx.x >> 7);
  int d = threadIdx.x & 127;
  int batch = gr / 3072;
  int ridx = gr - batch * 3072;
  int qt = 16 + (ridx >> 6);
  int rr = ridx & 63;
  int nc = 1 + (qt >> 4);
  int sb = (qt < 32) ? 16 + (qt - 16) * 2
         : (qt < 48) ? 48 + (qt - 32) * 3
                     : 96 + (qt - 48) * 4;
  size_t base = ((size_t)batch * 160 + sb) * 64 + rr;
  float mi[4], li[4];
  float M = -1e30f;
#pragma unroll
  for (int i = 0; i < 4; ++i) {
    if (i < nc) {
      mi[i] = pml[(base + (size_t)i * 64) * 2];
      li[i] = pml[(base + (size_t)i * 64) * 2 + 1];
      M = fmaxf(M, mi[i]);
    }
  }
  float L = 0.f, acc = 0.f;
#pragma unroll
  for (int i = 0; i < 4; ++i) {
    if (i < nc) {
      float sc = __expf(mi[i] - M);
      L += li[i] * sc;
      acc += po[(base + (size_t)i * 64) * 128 + d] * sc;
    }
  }
  out[((size_t)batch * T_SEQ + qt * 64 + rr) * HD + d] = acc / L;
}

extern "C" void kernel_launch(void* const* d_in, const int* in_sizes, int n_in,
                              void* d_out, int out_size, void* d_ws, size_t ws_size,
                              hipStream_t stream) {
  const float* x  = (const float*)d_in[0];
  const float* qw = (const float*)d_in[1];
  const float* qb = (const float*)d_in[2];
  const float* kw = (const float*)d_in[3];
  const float* kb = (const float*)d_in[4];
  const float* vw = (const float*)d_in[5];
  const float* vb = (const float*)d_in[6];
  float* out = (float*)d_out;

  unsigned short* qkv = (unsigned short*)d_ws;              // 12,582,912 B
  unsigned short* wb  = qkv + (size_t)16384 * 384;          //  1,572,864 B
  float* biasc = (float*)(wb + (size_t)384 * 2048);         //      1,536 B
  float* po  = (float*)((char*)d_ws + 14157312);            // 640*64*128*4 = 20,971,520 B
  float* pml = po + (size_t)640 * 64 * 128;                 // 640*64*2*4 = 327,680 B
  size_t need = 14157312 + (size_t)640 * 64 * 128 * 4 + (size_t)640 * 64 * 2 * 4;
  int split = (ws_size >= need) ? 1 : 0;

  cvt_w_kernel<<<768, 256, 0, stream>>>(qw, qb, kw, kb, vw, vb, wb, biasc);
  proj_kernel<<<dim3(256, 3), 256, 0, stream>>>(x, wb, biasc, qkv);
  attn_kernel<<<dim3(split ? 160 : 64, 4), 256, 0, stream>>>(qkv, out, po, pml, split);
  if (split)
    combine_kernel<<<6144, 256, 0, stream>>>(po, pml, out);
}